// Round 8
// baseline (343.162 us; speedup 1.0000x reference)
//
#include <hip/hip_runtime.h>

typedef __bf16 bf16_t;
typedef __bf16 bf16x8 __attribute__((ext_vector_type(8)));
typedef __bf16 bf16x4 __attribute__((ext_vector_type(4)));
typedef float  f32x4  __attribute__((ext_vector_type(4)));
typedef unsigned int u32;
typedef u32 u32x2 __attribute__((ext_vector_type(2)));
typedef u32 u32x4 __attribute__((ext_vector_type(4)));

#define LOG2E 1.44269504088896340736f

// ---------------------------------------------------------------- helpers
__device__ __forceinline__ void gload_lds16(const void* g, void* l) {
  __builtin_amdgcn_global_load_lds(
      (const __attribute__((address_space(1))) void*)g,
      (__attribute__((address_space(3))) void*)l, 16, 0, 0);
}

__device__ __forceinline__ void store_c(float* p, float v)  { *p = v; }
__device__ __forceinline__ void store_c(bf16_t* p, float v) { *p = (bf16_t)v; }

// ---------------------------------------------------------------- cast fp32 -> bf16
__global__ __launch_bounds__(256) void cast_kernel(const float* __restrict__ in,
                                                   bf16_t* __restrict__ out, int n4) {
  int i = blockIdx.x * 256 + threadIdx.x;
  const int stride = gridDim.x * 256;
  for (; i < n4; i += stride) {
    f32x4 v = *(const f32x4*)(in + (size_t)i * 4);
    bf16x4 o;
#pragma unroll
    for (int j = 0; j < 4; ++j) o[j] = (bf16_t)v[j];
    *(bf16x4*)(out + (size_t)i * 4) = o;
  }
}

// ---------------------------------------------------------------- GEMM  C[M][N] = A[M][K] * B[N][K]^T
template <typename OutT>
__global__ __launch_bounds__(256) void gemm_bt(const bf16_t* __restrict__ A,
                                               const bf16_t* __restrict__ B,
                                               OutT* __restrict__ C,
                                               int M, int N, int K) {
  __shared__ bf16_t As[128 * 32];
  __shared__ bf16_t Bs[128 * 32];
  const int tid  = threadIdx.x;
  const int lane = tid & 63;
  const int wid  = tid >> 6;
  const int wm = wid >> 1, wn = wid & 1;
  const size_t m0 = (size_t)blockIdx.y * 128;
  const size_t n0 = (size_t)blockIdx.x * 128;

  f32x4 acc[4][4] = {};

  for (int k0 = 0; k0 < K; k0 += 32) {
#pragma unroll
    for (int j = 0; j < 2; ++j) {
      const int c = tid + j * 256;
      const int r = c >> 2;
      const int kp = (c & 3) * 8;
      gload_lds16(A + (m0 + r) * K + k0 + kp, As + (size_t)c * 8);
      gload_lds16(B + (n0 + r) * K + k0 + kp, Bs + (size_t)c * 8);
    }
    __syncthreads();

    const int kk = (lane >> 4) * 8;
    const int rs = lane & 15;
    bf16x8 af[4], bfv[4];
#pragma unroll
    for (int t = 0; t < 4; ++t) {
      af[t]  = *(const bf16x8*)(As + (wm * 64 + t * 16 + rs) * 32 + kk);
      bfv[t] = *(const bf16x8*)(Bs + (wn * 64 + t * 16 + rs) * 32 + kk);
    }
#pragma unroll
    for (int mt = 0; mt < 4; ++mt)
#pragma unroll
      for (int nt = 0; nt < 4; ++nt)
        acc[mt][nt] = __builtin_amdgcn_mfma_f32_16x16x32_bf16(af[mt], bfv[nt], acc[mt][nt], 0, 0, 0);
    __syncthreads();
  }

#pragma unroll
  for (int mt = 0; mt < 4; ++mt)
#pragma unroll
    for (int nt = 0; nt < 4; ++nt)
#pragma unroll
      for (int r = 0; r < 4; ++r) {
        size_t row = m0 + wm * 64 + mt * 16 + (lane >> 4) * 4 + r;
        size_t col = n0 + wn * 64 + nt * 16 + (lane & 15);
        store_c(C + row * N + col, acc[mt][nt][r]);
      }
}

// ---------------------------------------------------------------- RoPE + reorg
__global__ __launch_bounds__(256) void rope_reorg(const bf16_t* __restrict__ qkv,
                                                  const float* __restrict__ cosT,
                                                  const float* __restrict__ sinT,
                                                  bf16_t* __restrict__ Q,
                                                  bf16_t* __restrict__ Kd,
                                                  bf16_t* __restrict__ Vt) {
  __shared__ bf16_t T[64 * 72];
  const int blk  = blockIdx.x;
  const int sblk = blk & 31;
  const int hh   = (blk >> 5) % 48;
  const int b    = blk / (32 * 48);
  const int s0   = sblk * 64;
  const int tid  = threadIdx.x;

  if (hh < 32) {
    const bool isq = hh < 16;
    const int h = isq ? hh : hh - 16;
    bf16_t* dst = (isq ? Q : Kd) + (size_t)(b * 16 + h) * 2048 * 64;
    for (int u = tid; u < 512; u += 256) {
      const int s = u >> 3, oct = u & 7;
      const size_t src = ((size_t)(b * 2048) + s0 + s) * 3072 + hh * 64;
      bf16x8 x = *(const bf16x8*)(qkv + src + oct * 8);
      bf16x8 y = *(const bf16x8*)(qkv + src + ((oct * 8) ^ 32));
      const float* cp = cosT + (size_t)(s0 + s) * 64 + oct * 8;
      const float* sp = sinT + (size_t)(s0 + s) * 64 + oct * 8;
      const float sgn = (oct < 4) ? -1.f : 1.f;
      bf16x8 ov;
#pragma unroll
      for (int j = 0; j < 8; ++j) {
        float xv = (float)x[j], yv = (float)y[j];
        ov[j] = (bf16_t)(xv * cp[j] + sgn * yv * sp[j]);
      }
      *(bf16x8*)(dst + (size_t)(s0 + s) * 64 + oct * 8) = ov;
    }
  } else {
    const int hv = hh - 32;
    for (int u = tid; u < 512; u += 256) {
      const int s = u >> 3, oct = u & 7;
      *(bf16x8*)(&T[s * 72 + oct * 8]) =
          *(const bf16x8*)(qkv + ((size_t)(b * 2048) + s0 + s) * 3072 + hh * 64 + oct * 8);
    }
    __syncthreads();
    bf16_t* dst = Vt + (size_t)(b * 16 + hv) * 64 * 2048;
    for (int u = tid; u < 512; u += 256) {
      const int d = u >> 3, soct = u & 7;
      bf16x8 w;
#pragma unroll
      for (int j = 0; j < 8; ++j) w[j] = T[(soct * 8 + j) * 72 + d];
      *(bf16x8*)(dst + (size_t)d * 2048 + s0 + soct * 8) = w;
    }
  }
}

// ---------------------------------------------------------------- flash attention v6
// Swapped-operand 16x16x32 (premise HW-verified: gemm_bt loads A/B frags with
// the identical pattern and passes vs numpy => A,B share slot->k mapping =>
// a common key-bijection kappa on P(B) and V^T(A) contracts correctly).
//  - mfma(K,Q): lane owns ONE query (l15), 16 keys/64-tile in regs.
//  - softmax: local 16-tree + 2 shfls; al,m,l are lane scalars.
//  - PV: P B-frag = local pack at kappa(g,j) = {4g+j | 16+4g+(j-4)};
//        V^T A-frag loaded at the same kappa offsets. No LDS, no barriers.
//  - XCD packing (4 bh/XCD) + K dbuf + early-V prefetch kept from v5.
__global__ __launch_bounds__(256) void attn_kernel(const bf16_t* __restrict__ Q,
                                                   const bf16_t* __restrict__ Kt,
                                                   const bf16_t* __restrict__ Vt,
                                                   bf16_t* __restrict__ O) {
  const int bid  = blockIdx.x;              // 1024 blocks, 1D
  const int xcd  = bid & 7;
  const int idx  = bid >> 3;
  const int bh   = xcd * 4 + (idx & 3);     // 4 bh per XCD
  const int qblk = 31 - (idx >> 2);         // heavy first
  const int b    = bh >> 4;
  const int h    = bh & 15;
  const int tid  = threadIdx.x;
  const int lane = tid & 63;
  const int wid  = tid >> 6;
  const bf16_t* Qb = Q  + (size_t)bh * 2048 * 64;
  const bf16_t* Kb = Kt + (size_t)bh * 2048 * 64;
  const bf16_t* Vb = Vt + (size_t)bh * 64 * 2048;

  const int q0  = qblk * 64 + wid * 16;     // wave's 16 query rows
  const int l15 = lane & 15;
  const int g   = lane >> 4;
  const int g4  = g * 4;
  const int dd  = g * 8;
  const int qg  = q0 + l15;                 // this lane's query
  const int qmax = q0 + 15;
  const int ntiles = qblk + 1;              // 64-key tiles (block-uniform)
  const float SC = 0.125f * LOG2E;

  // Q B-fragments: lane holds Q[q0+l15][dd..dd+7 (+32)]
  bf16x8 qf0 = *(const bf16x8*)(Qb + (size_t)qg * 64 + dd);
  bf16x8 qf1 = *(const bf16x8*)(Qb + (size_t)qg * 64 + 32 + dd);

  // O^T accumulators: o[dt][r] = O^T[d=16dt+4g+r][q=l15]
  f32x4 o[4] = {};
  float m_run = -3.0e38f, l_run = 0.f;

  auto prefK = [&](int tt, bf16x8 (&kf)[4][2]) {
    if (tt >= ntiles) return;
    const int kv0 = tt * 64;
#pragma unroll
    for (int kt = 0; kt < 4; ++kt) {
      const bf16_t* kp = Kb + (size_t)(kv0 + kt * 16 + l15) * 64;
      kf[kt][0] = *(const bf16x8*)(kp + dd);
      kf[kt][1] = *(const bf16x8*)(kp + 32 + dd);
    }
  };
  // V^T A-frag at kappa placement: chunk c (32 keys), row d = 16dt+l15:
  // slots j<4 -> keys kv0+32c+4g+j ; j>=4 -> keys kv0+32c+16+4g+(j-4)
  auto prefV = [&](int tt, bf16x4 (&vl)[2][4], bf16x4 (&vh)[2][4]) {
    if (tt >= ntiles) return;
    const int kv0 = tt * 64;
#pragma unroll
    for (int c = 0; c < 2; ++c)
#pragma unroll
      for (int dt = 0; dt < 4; ++dt) {
        const bf16_t* vp = Vb + (size_t)(dt * 16 + l15) * 2048 + kv0 + 32 * c + g4;
        vl[c][dt] = *(const bf16x4*)(vp);
        vh[c][dt] = *(const bf16x4*)(vp + 16);
      }
  };

  auto join = [](bf16x4 lo, bf16x4 hi2) -> bf16x8 {
    u32x2 a = __builtin_bit_cast(u32x2, lo);
    u32x2 c = __builtin_bit_cast(u32x2, hi2);
    u32x4 w = {a[0], a[1], c[0], c[1]};
    return __builtin_bit_cast(bf16x8, w);
  };

  auto compute = [&](bf16x8 (&kf)[4][2], bf16x4 (&vl)[2][4], bf16x4 (&vh)[2][4],
                     int kv0) {
    // ---- S^T = (Q K^T)^T : st[t][r] = S[q=l15][key=kv0+16t+4g+r]
    f32x4 st[4];
#pragma unroll
    for (int kt = 0; kt < 4; ++kt) {
      f32x4 acc = {};
      acc = __builtin_amdgcn_mfma_f32_16x16x32_bf16(kf[kt][0], qf0, acc, 0, 0, 0);
      acc = __builtin_amdgcn_mfma_f32_16x16x32_bf16(kf[kt][1], qf1, acc, 0, 0, 0);
      st[kt] = acc;
    }

    // ---- causal mask (diagonal tile only)
    if (kv0 + 63 > q0) {
#pragma unroll
      for (int kt = 0; kt < 4; ++kt)
#pragma unroll
        for (int r = 0; r < 4; ++r) {
          const int kg = kv0 + kt * 16 + g4 + r;
          st[kt][r] = (kg > qg) ? -1.0e30f : st[kt][r];
        }
    }

    // ---- online softmax: all stats lane-scalar for q=l15
    float mb = -3.0e38f;
#pragma unroll
    for (int kt = 0; kt < 4; ++kt) {
      float a = fmaxf(st[kt][0], st[kt][1]);
      float bm = fmaxf(st[kt][2], st[kt][3]);
      mb = fmaxf(mb, fmaxf(a, bm));
    }
    mb = fmaxf(mb, __shfl_xor(mb, 16));
    mb = fmaxf(mb, __shfl_xor(mb, 32));

    const float mn = fmaxf(m_run, mb);
    const float al = __builtin_amdgcn_exp2f((m_run - mn) * SC);
    m_run = mn;
    const float mc = mn * SC;

    float p[4][4];
    float lb = 0.f;
#pragma unroll
    for (int kt = 0; kt < 4; ++kt)
#pragma unroll
      for (int r = 0; r < 4; ++r) {
        p[kt][r] = __builtin_amdgcn_exp2f(__builtin_fmaf(st[kt][r], SC, -mc));
        lb += p[kt][r];
      }
    lb += __shfl_xor(lb, 16);
    lb += __shfl_xor(lb, 32);
    l_run = l_run * al + lb;

#pragma unroll
    for (int dt = 0; dt < 4; ++dt)
#pragma unroll
      for (int r = 0; r < 4; ++r) o[dt][r] *= al;

    // ---- P B-frags (pure local pack, kappa placement)
    bf16x8 pf0, pf1;
#pragma unroll
    for (int j = 0; j < 4; ++j) {
      pf0[j]     = (bf16_t)p[0][j];
      pf0[j + 4] = (bf16_t)p[1][j];
      pf1[j]     = (bf16_t)p[2][j];
      pf1[j + 4] = (bf16_t)p[3][j];
    }

    // ---- O^T += V^T P^T
#pragma unroll
    for (int dt = 0; dt < 4; ++dt)
      o[dt] = __builtin_amdgcn_mfma_f32_16x16x32_bf16(join(vl[0][dt], vh[0][dt]), pf0, o[dt], 0, 0, 0);
    if (kv0 + 32 <= qmax) {
#pragma unroll
      for (int dt = 0; dt < 4; ++dt)
        o[dt] = __builtin_amdgcn_mfma_f32_16x16x32_bf16(join(vl[1][dt], vh[1][dt]), pf1, o[dt], 0, 0, 0);
    }
  };

  bf16x8 ka[4][2], kb2[4][2];
  bf16x4 vcl[2][4], vch[2][4];
  prefK(0, ka);
  for (int t = 0; t < ntiles; t += 2) {
    prefK(t + 1, kb2);                      // next-tile K in flight
    prefV(t, vcl, vch);                     // this-tile V in flight during QK+softmax
    compute(ka, vcl, vch, t * 64);
    prefK(t + 2, ka);
    prefV(t + 1, vcl, vch);
    if (t + 1 < ntiles) compute(kb2, vcl, vch, (t + 1) * 64);
  }

  // ---- epilogue: O[q][h*64 + 16dt + 4g + r] = o[dt][r]/l
  const float inv = 1.f / l_run;
  bf16_t* Ob = O + ((size_t)(b * 2048) + qg) * 1024 + h * 64;
#pragma unroll
  for (int dt = 0; dt < 4; ++dt) {
    bf16x4 w;
#pragma unroll
    for (int r = 0; r < 4; ++r) w[r] = (bf16_t)(o[dt][r] * inv);
    *(bf16x4*)(Ob + dt * 16 + g4) = w;
  }
}

// ---------------------------------------------------------------- launch
extern "C" void kernel_launch(void* const* d_in, const int* in_sizes, int n_in,
                              void* d_out, int out_size, void* d_ws, size_t ws_size,
                              hipStream_t stream) {
  const float* hs   = (const float*)d_in[0];   // [2][2048][1024]
  const float* cosT = (const float*)d_in[1];   // [2048][64]
  const float* sinT = (const float*)d_in[2];   // [2048][64]
  const float* wqkv = (const float*)d_in[3];   // [3072][1024]
  const float* wo   = (const float*)d_in[4];   // [1024][1024]
  float* out = (float*)d_out;                  // [2][2048][1024]

  char* ws = (char*)d_ws;
  bf16_t* hs_b   = (bf16_t*)(ws);
  bf16_t* wqkv_b = (bf16_t*)(ws + 8388608);
  bf16_t* wo_b   = (bf16_t*)(ws + 14680064);
  bf16_t* qkv    = (bf16_t*)(ws + 16777216);
  bf16_t* Qb     = (bf16_t*)(ws + 41943040);
  bf16_t* Kb     = (bf16_t*)(ws + 50331648);
  bf16_t* Vtb    = (bf16_t*)(ws + 58720256);
  bf16_t* aout   = (bf16_t*)(ws + 67108864);

  cast_kernel<<<2048, 256, 0, stream>>>(hs,   hs_b,   4194304 / 4);
  cast_kernel<<<1024, 256, 0, stream>>>(wqkv, wqkv_b, 3145728 / 4);
  cast_kernel<<<512,  256, 0, stream>>>(wo,   wo_b,   1048576 / 4);

  gemm_bt<bf16_t><<<dim3(24, 32), 256, 0, stream>>>(hs_b, wqkv_b, qkv, 4096, 3072, 1024);

  rope_reorg<<<3072, 256, 0, stream>>>(qkv, cosT, sinT, Qb, Kb, Vtb);

  attn_kernel<<<1024, 256, 0, stream>>>(Qb, Kb, Vtb, aout);

  gemm_bt<float><<<dim3(8, 32), 256, 0, stream>>>(aout, wo_b, out, 4096, 1024, 1024);
}

// Round 9
// 334.482 us; speedup vs baseline: 1.0260x; 1.0260x over previous
//
#include <hip/hip_runtime.h>

typedef __bf16 bf16_t;
typedef __bf16 bf16x8 __attribute__((ext_vector_type(8)));
typedef __bf16 bf16x4 __attribute__((ext_vector_type(4)));
typedef float  f32x4  __attribute__((ext_vector_type(4)));
typedef unsigned int u32;
typedef u32 u32x2 __attribute__((ext_vector_type(2)));
typedef u32 u32x4 __attribute__((ext_vector_type(4)));

#define LOG2E 1.44269504088896340736f

// ---------------------------------------------------------------- helpers
__device__ __forceinline__ void gload_lds16(const void* g, void* l) {
  __builtin_amdgcn_global_load_lds(
      (const __attribute__((address_space(1))) void*)g,
      (__attribute__((address_space(3))) void*)l, 16, 0, 0);
}

__device__ __forceinline__ void store_c(float* p, float v)  { *p = v; }
__device__ __forceinline__ void store_c(bf16_t* p, float v) { *p = (bf16_t)v; }

// ---------------------------------------------------------------- cast fp32 -> bf16
__global__ __launch_bounds__(256) void cast_kernel(const float* __restrict__ in,
                                                   bf16_t* __restrict__ out, int n4) {
  int i = blockIdx.x * 256 + threadIdx.x;
  const int stride = gridDim.x * 256;
  for (; i < n4; i += stride) {
    f32x4 v = *(const f32x4*)(in + (size_t)i * 4);
    bf16x4 o;
#pragma unroll
    for (int j = 0; j < 4; ++j) o[j] = (bf16_t)v[j];
    *(bf16x4*)(out + (size_t)i * 4) = o;
  }
}

// ---------------------------------------------------------------- GEMM  C[M][N] = A[M][K] * B[N][K]^T
template <typename OutT>
__global__ __launch_bounds__(256) void gemm_bt(const bf16_t* __restrict__ A,
                                               const bf16_t* __restrict__ B,
                                               OutT* __restrict__ C,
                                               int M, int N, int K) {
  __shared__ bf16_t As[128 * 32];
  __shared__ bf16_t Bs[128 * 32];
  const int tid  = threadIdx.x;
  const int lane = tid & 63;
  const int wid  = tid >> 6;
  const int wm = wid >> 1, wn = wid & 1;
  const size_t m0 = (size_t)blockIdx.y * 128;
  const size_t n0 = (size_t)blockIdx.x * 128;

  f32x4 acc[4][4] = {};

  for (int k0 = 0; k0 < K; k0 += 32) {
#pragma unroll
    for (int j = 0; j < 2; ++j) {
      const int c = tid + j * 256;
      const int r = c >> 2;
      const int kp = (c & 3) * 8;
      gload_lds16(A + (m0 + r) * K + k0 + kp, As + (size_t)c * 8);
      gload_lds16(B + (n0 + r) * K + k0 + kp, Bs + (size_t)c * 8);
    }
    __syncthreads();

    const int kk = (lane >> 4) * 8;
    const int rs = lane & 15;
    bf16x8 af[4], bfv[4];
#pragma unroll
    for (int t = 0; t < 4; ++t) {
      af[t]  = *(const bf16x8*)(As + (wm * 64 + t * 16 + rs) * 32 + kk);
      bfv[t] = *(const bf16x8*)(Bs + (wn * 64 + t * 16 + rs) * 32 + kk);
    }
#pragma unroll
    for (int mt = 0; mt < 4; ++mt)
#pragma unroll
      for (int nt = 0; nt < 4; ++nt)
        acc[mt][nt] = __builtin_amdgcn_mfma_f32_16x16x32_bf16(af[mt], bfv[nt], acc[mt][nt], 0, 0, 0);
    __syncthreads();
  }

#pragma unroll
  for (int mt = 0; mt < 4; ++mt)
#pragma unroll
    for (int nt = 0; nt < 4; ++nt)
#pragma unroll
      for (int r = 0; r < 4; ++r) {
        size_t row = m0 + wm * 64 + mt * 16 + (lane >> 4) * 4 + r;
        size_t col = n0 + wn * 64 + nt * 16 + (lane & 15);
        store_c(C + row * N + col, acc[mt][nt][r]);
      }
}

// ---------------------------------------------------------------- RoPE + reorg
__global__ __launch_bounds__(256) void rope_reorg(const bf16_t* __restrict__ qkv,
                                                  const float* __restrict__ cosT,
                                                  const float* __restrict__ sinT,
                                                  bf16_t* __restrict__ Q,
                                                  bf16_t* __restrict__ Kd,
                                                  bf16_t* __restrict__ Vt) {
  __shared__ bf16_t T[64 * 72];
  const int blk  = blockIdx.x;
  const int sblk = blk & 31;
  const int hh   = (blk >> 5) % 48;
  const int b    = blk / (32 * 48);
  const int s0   = sblk * 64;
  const int tid  = threadIdx.x;

  if (hh < 32) {
    const bool isq = hh < 16;
    const int h = isq ? hh : hh - 16;
    bf16_t* dst = (isq ? Q : Kd) + (size_t)(b * 16 + h) * 2048 * 64;
    for (int u = tid; u < 512; u += 256) {
      const int s = u >> 3, oct = u & 7;
      const size_t src = ((size_t)(b * 2048) + s0 + s) * 3072 + hh * 64;
      bf16x8 x = *(const bf16x8*)(qkv + src + oct * 8);
      bf16x8 y = *(const bf16x8*)(qkv + src + ((oct * 8) ^ 32));
      const float* cp = cosT + (size_t)(s0 + s) * 64 + oct * 8;
      const float* sp = sinT + (size_t)(s0 + s) * 64 + oct * 8;
      const float sgn = (oct < 4) ? -1.f : 1.f;
      bf16x8 ov;
#pragma unroll
      for (int j = 0; j < 8; ++j) {
        float xv = (float)x[j], yv = (float)y[j];
        ov[j] = (bf16_t)(xv * cp[j] + sgn * yv * sp[j]);
      }
      *(bf16x8*)(dst + (size_t)(s0 + s) * 64 + oct * 8) = ov;
    }
  } else {
    const int hv = hh - 32;
    for (int u = tid; u < 512; u += 256) {
      const int s = u >> 3, oct = u & 7;
      *(bf16x8*)(&T[s * 72 + oct * 8]) =
          *(const bf16x8*)(qkv + ((size_t)(b * 2048) + s0 + s) * 3072 + hh * 64 + oct * 8);
    }
    __syncthreads();
    bf16_t* dst = Vt + (size_t)(b * 16 + hv) * 64 * 2048;
    for (int u = tid; u < 512; u += 256) {
      const int d = u >> 3, soct = u & 7;
      bf16x8 w;
#pragma unroll
      for (int j = 0; j < 8; ++j) w[j] = T[(soct * 8 + j) * 72 + d];
      *(bf16x8*)(dst + (size_t)d * 2048 + s0 + soct * 8) = w;
    }
  }
}

// ---------------------------------------------------------------- flash attention v7
// v6's HW-verified swapped-operand math (passed R8), restructured for latency:
//  - UNIFORM WORK: each wave does complementary qblk pair (31-pj then pj)
//    = exactly 33 key-tiles -> zero drain tail. 512 blocks, 2 blocks/CU.
//  - SINGLE-BUFFER ROLLING PREFETCH: K(t+1) loads issue right after tile t's
//    QK MFMAs (K regs dead); V(t+1) right after PV. ~400cy slack each, and
//    the live set fits the register budget so the compiler keeps the loads
//    hoisted (v5/v6 had them silently sunk to use sites -> serial L2 stalls).
//  - XCD packing (4 bh/XCD) kept: K/V L2-resident (FETCH 12.3MB confirmed).
__global__ __launch_bounds__(256, 2) void attn_kernel(const bf16_t* __restrict__ Q,
                                                      const bf16_t* __restrict__ Kt,
                                                      const bf16_t* __restrict__ Vt,
                                                      bf16_t* __restrict__ O) {
  const int bid  = blockIdx.x;              // 512 blocks
  const int xcd  = bid & 7;
  const int idx  = bid >> 3;                // 0..63
  const int bh   = xcd * 4 + (idx & 3);     // 4 bh per XCD
  const int pj   = idx >> 2;                // 0..15 pair index
  const int b    = bh >> 4;
  const int h    = bh & 15;
  const int tid  = threadIdx.x;
  const int lane = tid & 63;
  const int wid  = tid >> 6;
  const int l15  = lane & 15;
  const int g    = lane >> 4;
  const int g4   = g * 4;
  const int dd   = g * 8;
  const bf16_t* Qb = Q  + (size_t)bh * 2048 * 64;
  const bf16_t* Kb = Kt + (size_t)bh * 2048 * 64;
  const bf16_t* Vb = Vt + (size_t)bh * 64 * 2048;
  const float SC = 0.125f * LOG2E;

  bf16x8 kf[4][2];                          // current K tile (rolling)
  bf16x4 vl[2][4], vh[2][4];                // current V tile (rolling)

  auto join = [](bf16x4 lo, bf16x4 hi2) -> bf16x8 {
    u32x2 a = __builtin_bit_cast(u32x2, lo);
    u32x2 c = __builtin_bit_cast(u32x2, hi2);
    u32x4 w = {a[0], a[1], c[0], c[1]};
    return __builtin_bit_cast(bf16x8, w);
  };

  for (int phase = 0; phase < 2; ++phase) {
    const int qblk = (phase == 0) ? (31 - pj) : pj;   // heavy first
    const int q0   = qblk * 64 + wid * 16;
    const int qg   = q0 + l15;              // this lane's query
    const int ntiles = qblk + 1;

    // Q B-fragments
    bf16x8 qf0 = *(const bf16x8*)(Qb + (size_t)qg * 64 + dd);
    bf16x8 qf1 = *(const bf16x8*)(Qb + (size_t)qg * 64 + 32 + dd);

    f32x4 o[4] = {};                        // O^T accum: o[dt][r], q=l15
    float m_run = -3.0e38f, l_run = 0.f;

    // initial K+V fill (tile 0)
#pragma unroll
    for (int kt = 0; kt < 4; ++kt) {
      const bf16_t* kp = Kb + (size_t)(kt * 16 + l15) * 64;
      kf[kt][0] = *(const bf16x8*)(kp + dd);
      kf[kt][1] = *(const bf16x8*)(kp + 32 + dd);
    }
#pragma unroll
    for (int c = 0; c < 2; ++c)
#pragma unroll
      for (int dt = 0; dt < 4; ++dt) {
        const bf16_t* vp = Vb + (size_t)(dt * 16 + l15) * 2048 + 32 * c + g4;
        vl[c][dt] = *(const bf16x4*)(vp);
        vh[c][dt] = *(const bf16x4*)(vp + 16);
      }

    for (int t = 0; t < ntiles; ++t) {
      const int kv0 = t * 64;

      // ---- S^T: st[kt][r] = S[q=l15][key=kv0+16kt+4g+r]
      f32x4 st[4];
#pragma unroll
      for (int kt = 0; kt < 4; ++kt) {
        f32x4 acc = {};
        acc = __builtin_amdgcn_mfma_f32_16x16x32_bf16(kf[kt][0], qf0, acc, 0, 0, 0);
        acc = __builtin_amdgcn_mfma_f32_16x16x32_bf16(kf[kt][1], qf1, acc, 0, 0, 0);
        st[kt] = acc;
      }

      // ---- prefetch K(t+1): kf regs are dead after the QK MFMAs above;
      //      slack = softmax + PV (~400cy) before next-iteration use.
      if (t + 1 < ntiles) {
        const int kn = kv0 + 64;
#pragma unroll
        for (int kt = 0; kt < 4; ++kt) {
          const bf16_t* kp = Kb + (size_t)(kn + kt * 16 + l15) * 64;
          kf[kt][0] = *(const bf16x8*)(kp + dd);
          kf[kt][1] = *(const bf16x8*)(kp + 32 + dd);
        }
      }

      // ---- causal mask (diagonal tile only)
      if (kv0 + 63 > q0) {
#pragma unroll
        for (int kt = 0; kt < 4; ++kt)
#pragma unroll
          for (int r = 0; r < 4; ++r) {
            const int kg = kv0 + kt * 16 + g4 + r;
            st[kt][r] = (kg > qg) ? -1.0e30f : st[kt][r];
          }
      }

      // ---- online softmax (lane-scalar stats, 2+2 shfls)
      float mb = -3.0e38f;
#pragma unroll
      for (int kt = 0; kt < 4; ++kt) {
        float a = fmaxf(st[kt][0], st[kt][1]);
        float bm = fmaxf(st[kt][2], st[kt][3]);
        mb = fmaxf(mb, fmaxf(a, bm));
      }
      mb = fmaxf(mb, __shfl_xor(mb, 16));
      mb = fmaxf(mb, __shfl_xor(mb, 32));

      const float mn = fmaxf(m_run, mb);
      const float al = __builtin_amdgcn_exp2f((m_run - mn) * SC);
      m_run = mn;
      const float mc = mn * SC;

      float lb = 0.f;
      bf16x8 pf0, pf1;
#pragma unroll
      for (int kt = 0; kt < 4; ++kt) {
        float pv[4];
#pragma unroll
        for (int r = 0; r < 4; ++r) {
          pv[r] = __builtin_amdgcn_exp2f(__builtin_fmaf(st[kt][r], SC, -mc));
          lb += pv[r];
        }
#pragma unroll
        for (int r = 0; r < 4; ++r) {
          if (kt == 0) pf0[r]     = (bf16_t)pv[r];
          if (kt == 1) pf0[r + 4] = (bf16_t)pv[r];
          if (kt == 2) pf1[r]     = (bf16_t)pv[r];
          if (kt == 3) pf1[r + 4] = (bf16_t)pv[r];
        }
      }
      lb += __shfl_xor(lb, 16);
      lb += __shfl_xor(lb, 32);
      l_run = l_run * al + lb;

#pragma unroll
      for (int dt = 0; dt < 4; ++dt)
#pragma unroll
        for (int r = 0; r < 4; ++r) o[dt][r] *= al;

      // ---- O^T += V^T P^T (kappa placement both sides — HW-verified R8)
#pragma unroll
      for (int dt = 0; dt < 4; ++dt)
        o[dt] = __builtin_amdgcn_mfma_f32_16x16x32_bf16(join(vl[0][dt], vh[0][dt]), pf0, o[dt], 0, 0, 0);
      if (kv0 + 32 <= q0 + 15) {
#pragma unroll
        for (int dt = 0; dt < 4; ++dt)
          o[dt] = __builtin_amdgcn_mfma_f32_16x16x32_bf16(join(vl[1][dt], vh[1][dt]), pf1, o[dt], 0, 0, 0);
      }

      // ---- prefetch V(t+1): vl/vh dead after PV; slack = next QK+softmax.
      if (t + 1 < ntiles) {
        const int kn = kv0 + 64;
#pragma unroll
        for (int c = 0; c < 2; ++c)
#pragma unroll
          for (int dt = 0; dt < 4; ++dt) {
            const bf16_t* vp = Vb + (size_t)(dt * 16 + l15) * 2048 + kn + 32 * c + g4;
            vl[c][dt] = *(const bf16x4*)(vp);
            vh[c][dt] = *(const bf16x4*)(vp + 16);
          }
      }
    }

    // ---- epilogue: O[q][h*64 + 16dt + 4g + r]
    const float inv = 1.f / l_run;
    bf16_t* Ob = O + ((size_t)(b * 2048) + qg) * 1024 + h * 64;
#pragma unroll
    for (int dt = 0; dt < 4; ++dt) {
      bf16x4 w;
#pragma unroll
      for (int r = 0; r < 4; ++r) w[r] = (bf16_t)(o[dt][r] * inv);
      *(bf16x4*)(Ob + dt * 16 + g4) = w;
    }
  }
}

// ---------------------------------------------------------------- launch
extern "C" void kernel_launch(void* const* d_in, const int* in_sizes, int n_in,
                              void* d_out, int out_size, void* d_ws, size_t ws_size,
                              hipStream_t stream) {
  const float* hs   = (const float*)d_in[0];   // [2][2048][1024]
  const float* cosT = (const float*)d_in[1];   // [2048][64]
  const float* sinT = (const float*)d_in[2];   // [2048][64]
  const float* wqkv = (const float*)d_in[3];   // [3072][1024]
  const float* wo   = (const float*)d_in[4];   // [1024][1024]
  float* out = (float*)d_out;                  // [2][2048][1024]

  char* ws = (char*)d_ws;
  bf16_t* hs_b   = (bf16_t*)(ws);
  bf16_t* wqkv_b = (bf16_t*)(ws + 8388608);
  bf16_t* wo_b   = (bf16_t*)(ws + 14680064);
  bf16_t* qkv    = (bf16_t*)(ws + 16777216);
  bf16_t* Qb     = (bf16_t*)(ws + 41943040);
  bf16_t* Kb     = (bf16_t*)(ws + 50331648);
  bf16_t* Vtb    = (bf16_t*)(ws + 58720256);
  bf16_t* aout   = (bf16_t*)(ws + 67108864);

  cast_kernel<<<2048, 256, 0, stream>>>(hs,   hs_b,   4194304 / 4);
  cast_kernel<<<1024, 256, 0, stream>>>(wqkv, wqkv_b, 3145728 / 4);
  cast_kernel<<<512,  256, 0, stream>>>(wo,   wo_b,   1048576 / 4);

  gemm_bt<bf16_t><<<dim3(24, 32), 256, 0, stream>>>(hs_b, wqkv_b, qkv, 4096, 3072, 1024);

  rope_reorg<<<3072, 256, 0, stream>>>(qkv, cosT, sinT, Qb, Kb, Vtb);

  attn_kernel<<<512, 256, 0, stream>>>(Qb, Kb, Vtb, aout);

  gemm_bt<float><<<dim3(8, 32), 256, 0, stream>>>(aout, wo_b, out, 4096, 1024, 1024);
}